// Round 1
// baseline (242.850 us; speedup 1.0000x reference)
//
#include <hip/hip_runtime.h>
#include <math.h>

#define CC 256   // clusters
#define KK 16    // cluster size
#define DD 256   // embed dim
#define NN 4096  // CC*KK
#define TJ 256   // j-tile width
#define DCH 64   // d-chunk
#define JHALF 2048
#define EPSV 1e-6f

// ---------------- kernel 0: squared norms, one wave per row ----------------
__global__ __launch_bounds__(256) void sqnorm_kernel(const float* __restrict__ emb,
                                                     float* __restrict__ sq) {
  int gw = (blockIdx.x * 256 + threadIdx.x) >> 6;  // global wave id = row
  int lane = threadIdx.x & 63;
  if (gw >= NN) return;
  float4 v = *reinterpret_cast<const float4*>(emb + (size_t)gw * DD + 4 * lane);
  float s = v.x * v.x + v.y * v.y + v.z * v.z + v.w * v.w;
  #pragma unroll
  for (int off = 32; off; off >>= 1) s += __shfl_xor(s, off);
  if (lane == 0) sq[gw] = s;
}

// ---------------- kernel 1: batch-hard mining ----------------
// grid = CC*2 blocks: block -> (cluster c, j-half). 256 threads = 4 waves.
// wave w owns rows i = 16c + 4w .. +3 ; lane owns j = jt + 4*lane .. +3
__global__ __launch_bounds__(256) void mine_kernel(const float* __restrict__ emb,
                                                   const float* __restrict__ sq,
                                                   float* __restrict__ posval,
                                                   int* __restrict__ posidx,
                                                   float* __restrict__ negval,
                                                   int* __restrict__ negidx) {
  __shared__ float sB[DCH][TJ];  // d-major j-tile (64 KB)
  __shared__ float sA[DCH][KK];  // d-major own-cluster rows (4 KB)

  const int bx = blockIdx.x;
  const int c = bx >> 1;
  const int half = bx & 1;
  const int jbase = half * JHALF;
  const int tid = threadIdx.x;
  const int lane = tid & 63;
  const int w = tid >> 6;
  const int ibase = c * KK;

  float pv[4], nv[4];
  int pi[4], ni[4];
  #pragma unroll
  for (int ii = 0; ii < 4; ++ii) {
    pv[ii] = -1.0f; pi[ii] = 0x7fffffff;   // matches jnp where(mask, dist, -1)
    nv[ii] = 1e30f; ni[ii] = 0x7fffffff;
  }

  float sqi[4];
  {
    float4 s4 = *reinterpret_cast<const float4*>(sq + ibase + 4 * w);
    sqi[0] = s4.x; sqi[1] = s4.y; sqi[2] = s4.z; sqi[3] = s4.w;
  }

  for (int jt = jbase; jt < jbase + JHALF; jt += TJ) {
    float acc[4][4];
    #pragma unroll
    for (int ii = 0; ii < 4; ++ii)
      #pragma unroll
      for (int jj = 0; jj < 4; ++jj) acc[ii][jj] = 0.0f;

    for (int dc = 0; dc < DD; dc += DCH) {
      __syncthreads();  // protect LDS from previous tile's readers
      // stage sA: 64 d x 16 rows (transpose in flight)
      {
        int r = tid & 15, d0 = (tid >> 4) * 4;
        float4 v = *reinterpret_cast<const float4*>(emb + (size_t)(ibase + r) * DD + dc + d0);
        sA[d0 + 0][r] = v.x; sA[d0 + 1][r] = v.y;
        sA[d0 + 2][r] = v.z; sA[d0 + 3][r] = v.w;
      }
      // stage sB: thread t handles row j = jt + t (L1-resident row chunk)
      {
        const float* src = emb + (size_t)(jt + tid) * DD + dc;
        #pragma unroll
        for (int g = 0; g < 16; ++g) {
          float4 v = *reinterpret_cast<const float4*>(src + 4 * g);
          sB[4 * g + 0][tid] = v.x; sB[4 * g + 1][tid] = v.y;
          sB[4 * g + 2][tid] = v.z; sB[4 * g + 3][tid] = v.w;
        }
      }
      __syncthreads();
      // 4x4 micro-tile dot accumulation
      #pragma unroll 8
      for (int d = 0; d < DCH; ++d) {
        float4 a4 = *reinterpret_cast<const float4*>(&sA[d][4 * w]);     // broadcast
        float4 b4 = *reinterpret_cast<const float4*>(&sB[d][4 * lane]);  // stride-1 b128
        float a[4] = {a4.x, a4.y, a4.z, a4.w};
        float b[4] = {b4.x, b4.y, b4.z, b4.w};
        #pragma unroll
        for (int ii = 0; ii < 4; ++ii)
          #pragma unroll
          for (int jj = 0; jj < 4; ++jj)
            acc[ii][jj] = fmaf(a[ii], b[jj], acc[ii][jj]);
      }
    }

    // update running candidates (j strictly increasing per thread -> strict
    // compare keeps first occurrence, matching argmax/argmin)
    float4 sj4 = *reinterpret_cast<const float4*>(sq + jt + 4 * lane);
    float sqj[4] = {sj4.x, sj4.y, sj4.z, sj4.w};
    #pragma unroll
    for (int ii = 0; ii < 4; ++ii) {
      #pragma unroll
      for (int jj = 0; jj < 4; ++jj) {
        int j = jt + 4 * lane + jj;
        float d2 = fmaxf(sqi[ii] + sqj[jj] - 2.0f * acc[ii][jj], 0.0f);
        float dist = sqrtf(d2);
        if ((j >> 4) == c) {
          if (dist > pv[ii]) { pv[ii] = dist; pi[ii] = j; }
        } else {
          if (dist < nv[ii]) { nv[ii] = dist; ni[ii] = j; }
        }
      }
    }
  }

  // wave butterfly reduce with first-index tie-break
  #pragma unroll
  for (int ii = 0; ii < 4; ++ii) {
    float v = pv[ii]; int idx = pi[ii];
    #pragma unroll
    for (int off = 32; off; off >>= 1) {
      float ov = __shfl_xor(v, off);
      int oi = __shfl_xor(idx, off);
      if (ov > v || (ov == v && oi < idx)) { v = ov; idx = oi; }
    }
    float mv = nv[ii]; int midx = ni[ii];
    #pragma unroll
    for (int off = 32; off; off >>= 1) {
      float ov = __shfl_xor(mv, off);
      int oi = __shfl_xor(midx, off);
      if (ov < mv || (ov == mv && oi < midx)) { mv = ov; midx = oi; }
    }
    if (lane == 0) {
      int i = ibase + 4 * w + ii;
      posval[half * NN + i] = v;  posidx[half * NN + i] = idx;
      negval[half * NN + i] = mv; negidx[half * NN + i] = midx;
    }
  }
}

// ---------------- kernel 2: combine halves + triplet terms, wave per row ----
__global__ __launch_bounds__(256) void triplet_kernel(const float* __restrict__ emb,
                                                      const float* __restrict__ posval,
                                                      const int* __restrict__ posidx,
                                                      const float* __restrict__ negval,
                                                      const int* __restrict__ negidx,
                                                      float* __restrict__ hinge) {
  int i = (blockIdx.x * 256 + threadIdx.x) >> 6;
  int lane = threadIdx.x & 63;
  if (i >= NN) return;

  // half0 indices are all smaller than half1's -> ties pick half0 (first idx)
  float pv0 = posval[i], pv1 = posval[NN + i];
  int p = (pv0 >= pv1) ? posidx[i] : posidx[NN + i];
  float nv0 = negval[i], nv1 = negval[NN + i];
  int nidx = (nv0 <= nv1) ? negidx[i] : negidx[NN + i];

  float4 e  = *reinterpret_cast<const float4*>(emb + (size_t)i * DD + 4 * lane);
  float4 ep = *reinterpret_cast<const float4*>(emb + (size_t)p * DD + 4 * lane);
  float4 en = *reinterpret_cast<const float4*>(emb + (size_t)nidx * DD + 4 * lane);

  float dpx = e.x - ep.x + EPSV, dpy = e.y - ep.y + EPSV,
        dpz = e.z - ep.z + EPSV, dpw = e.w - ep.w + EPSV;
  float dnx = e.x - en.x + EPSV, dny = e.y - en.y + EPSV,
        dnz = e.z - en.z + EPSV, dnw = e.w - en.w + EPSV;
  float sp = dpx * dpx + dpy * dpy + dpz * dpz + dpw * dpw;
  float sn = dnx * dnx + dny * dny + dnz * dnz + dnw * dnw;
  #pragma unroll
  for (int off = 32; off; off >>= 1) {
    sp += __shfl_xor(sp, off);
    sn += __shfl_xor(sn, off);
  }
  if (lane == 0) {
    float d_ap = sqrtf(sp), d_an = sqrtf(sn);
    hinge[i] = fmaxf(d_ap - d_an + 1.0f, 0.0f);
  }
}

// ---------------- kernel 3: deterministic mean ----------------
__global__ __launch_bounds__(256) void reduce_kernel(const float* __restrict__ hinge,
                                                     float* __restrict__ out) {
  __shared__ float sdata[256];
  float s = 0.0f;
  for (int k = threadIdx.x; k < NN; k += 256) s += hinge[k];
  sdata[threadIdx.x] = s;
  __syncthreads();
  for (int st = 128; st; st >>= 1) {
    if (threadIdx.x < st) sdata[threadIdx.x] += sdata[threadIdx.x + st];
    __syncthreads();
  }
  if (threadIdx.x == 0) out[0] = sdata[0] * (1.0f / NN);
}

extern "C" void kernel_launch(void* const* d_in, const int* in_sizes, int n_in,
                              void* d_out, int out_size, void* d_ws, size_t ws_size,
                              hipStream_t stream) {
  const float* emb = (const float*)d_in[0];  // [N, D] row-major (reshape is a no-op)
  float* ws = (float*)d_ws;
  float* sq     = ws;               // 4096 floats
  float* posval = ws + 4096;        // 8192 floats (2 halves)
  float* negval = ws + 12288;       // 8192 floats
  float* hinge  = ws + 20480;       // 4096 floats
  int* posidx   = (int*)(ws + 24576);  // 8192 ints
  int* negidx   = (int*)(ws + 32768);  // 8192 ints
  float* out = (float*)d_out;

  sqnorm_kernel<<<NN / 4, 256, 0, stream>>>(emb, sq);
  mine_kernel<<<CC * 2, 256, 0, stream>>>(emb, sq, posval, posidx, negval, negidx);
  triplet_kernel<<<NN / 4, 256, 0, stream>>>(emb, posval, posidx, negval, negidx, hinge);
  reduce_kernel<<<1, 256, 0, stream>>>(hinge, out);
}

// Round 2
// 117.421 us; speedup vs baseline: 2.0682x; 2.0682x over previous
//
#include <hip/hip_runtime.h>
#include <math.h>

#define CC 256
#define KK 16
#define DD 256
#define NN 4096
#define EPSV 1e-6f

typedef unsigned long long u64;
typedef __attribute__((ext_vector_type(8))) short short8v;
typedef __attribute__((ext_vector_type(8))) unsigned short ushort8v;
typedef __attribute__((ext_vector_type(4))) float f32x4;

// ---------------- kernel 0: squared norms + init mining keys ----------------
__global__ __launch_bounds__(256) void sqnorm_kernel(const float* __restrict__ emb,
                                                     float* __restrict__ sq,
                                                     u64* __restrict__ posk,
                                                     u64* __restrict__ negk) {
  int gw = (blockIdx.x * 256 + threadIdx.x) >> 6;  // row
  int lane = threadIdx.x & 63;
  if (gw >= NN) return;
  float4 v = *reinterpret_cast<const float4*>(emb + (size_t)gw * DD + 4 * lane);
  float s = v.x * v.x + v.y * v.y + v.z * v.z + v.w * v.w;
  #pragma unroll
  for (int off = 32; off; off >>= 1) s += __shfl_xor(s, off);
  if (lane == 0) sq[gw] = s;
  if (lane == 1) posk[gw] = 0ull;          // min pos key
  if (lane == 2) negk[gw] = ~0ull;         // max neg key
}

// ---------------- kernel 1: MFMA gram-tile mining ----------------
// grid 32x32 blocks of 128x128 output tile. 256 threads = 4 waves (2x2 of 64x64).
// Split-bf16 3-pass: G ~= Ahh + Ahl + Alh accumulated in fp32 AGPRs.
__device__ __forceinline__ void split8(float4 v0, float4 v1, ushort8v& h, ushort8v& l) {
  float f[8] = {v0.x, v0.y, v0.z, v0.w, v1.x, v1.y, v1.z, v1.w};
  #pragma unroll
  for (int i = 0; i < 8; ++i) {
    unsigned b = __float_as_uint(f[i]);
    h[i] = (unsigned short)(b >> 16);                        // truncate to bf16
    float fl = f[i] - __uint_as_float(b & 0xFFFF0000u);      // exact residual
    l[i] = (unsigned short)(__float_as_uint(fl) >> 16);
  }
}

__global__ __launch_bounds__(256, 2) void mine_mfma_kernel(const float* __restrict__ emb,
                                                           const float* __restrict__ sq,
                                                           u64* __restrict__ posk,
                                                           u64* __restrict__ negk) {
  __shared__ __attribute__((aligned(16))) unsigned short sAhi[128][72];
  __shared__ __attribute__((aligned(16))) unsigned short sAlo[128][72];
  __shared__ __attribute__((aligned(16))) unsigned short sBhi[128][72];
  __shared__ __attribute__((aligned(16))) unsigned short sBlo[128][72];
  __shared__ float sSqI[128], sSqJ[128];

  const int tid = threadIdx.x;
  const int lane = tid & 63;
  const int w = tid >> 6;
  const int wm = w >> 1, wn = w & 1;
  const int ib = blockIdx.x >> 5, jb = blockIdx.x & 31;
  const int ibRow = ib * 128, jbRow = jb * 128;
  const bool diag = (ib == jb);

  if (tid < 128) sSqI[tid] = sq[ibRow + tid];
  else           sSqJ[tid - 128] = sq[jbRow + tid - 128];

  f32x4 acc[4][4];
  #pragma unroll
  for (int m = 0; m < 4; ++m)
    #pragma unroll
    for (int n = 0; n < 4; ++n)
      acc[m][n] = (f32x4){0.f, 0.f, 0.f, 0.f};

  const int tr = tid >> 3;          // 0..31 (row within pass-group)
  const int tc = (tid & 7) * 8;     // k-offset in floats
  const int fr = lane & 15;
  const int fkb = (lane >> 4) * 8;

  #pragma unroll
  for (int kt = 0; kt < 4; ++kt) {
    const int kc = kt * 64;
    __syncthreads();
    // stage A and B tiles: fp32 -> (hi,lo) bf16, padded rows (stride 72)
    #pragma unroll
    for (int p = 0; p < 4; ++p) {
      const int r = p * 32 + tr;
      {
        const float* s = emb + (size_t)(ibRow + r) * DD + kc + tc;
        float4 v0 = *reinterpret_cast<const float4*>(s);
        float4 v1 = *reinterpret_cast<const float4*>(s + 4);
        ushort8v h, l; split8(v0, v1, h, l);
        *reinterpret_cast<ushort8v*>(&sAhi[r][tc]) = h;
        *reinterpret_cast<ushort8v*>(&sAlo[r][tc]) = l;
      }
      {
        const float* s = emb + (size_t)(jbRow + r) * DD + kc + tc;
        float4 v0 = *reinterpret_cast<const float4*>(s);
        float4 v1 = *reinterpret_cast<const float4*>(s + 4);
        ushort8v h, l; split8(v0, v1, h, l);
        *reinterpret_cast<ushort8v*>(&sBhi[r][tc]) = h;
        *reinterpret_cast<ushort8v*>(&sBlo[r][tc]) = l;
      }
    }
    __syncthreads();

    #pragma unroll
    for (int s = 0; s < 2; ++s) {
      const int kl = s * 32 + fkb;
      short8v ahi[4], alo[4], bhi[4], blo[4];
      #pragma unroll
      for (int m = 0; m < 4; ++m) {
        const int ra = wm * 64 + m * 16 + fr;
        ahi[m] = *reinterpret_cast<const short8v*>(&sAhi[ra][kl]);
        alo[m] = *reinterpret_cast<const short8v*>(&sAlo[ra][kl]);
      }
      #pragma unroll
      for (int n = 0; n < 4; ++n) {
        const int rb = wn * 64 + n * 16 + fr;
        bhi[n] = *reinterpret_cast<const short8v*>(&sBhi[rb][kl]);
        blo[n] = *reinterpret_cast<const short8v*>(&sBlo[rb][kl]);
      }
      #pragma unroll
      for (int m = 0; m < 4; ++m)
        #pragma unroll
        for (int n = 0; n < 4; ++n) {
          acc[m][n] = __builtin_amdgcn_mfma_f32_16x16x32_bf16(ahi[m], bhi[n], acc[m][n], 0, 0, 0);
          acc[m][n] = __builtin_amdgcn_mfma_f32_16x16x32_bf16(ahi[m], blo[n], acc[m][n], 0, 0, 0);
          acc[m][n] = __builtin_amdgcn_mfma_f32_16x16x32_bf16(alo[m], bhi[n], acc[m][n], 0, 0, 0);
        }
    }
  }

  // ---- epilogue: per-row reduce over this tile's 128 columns, via d^2 ----
  // C layout (16x16x32): col = lane&15, row = (lane>>4)*4 + reg
  float sqjv[4]; int jglob[4];
  #pragma unroll
  for (int n = 0; n < 4; ++n) {
    const int cl = wn * 64 + n * 16 + fr;
    jglob[n] = jbRow + cl;
    sqjv[n] = sSqJ[cl];
  }

  #pragma unroll
  for (int m = 0; m < 4; ++m) {
    #pragma unroll
    for (int r = 0; r < 4; ++r) {
      const int il = wm * 64 + m * 16 + (lane >> 4) * 4 + r;
      const int gi = ibRow + il;
      const float sqiv = sSqI[il];
      float pv = -1.0f; int pj = -1;
      float nv = 3.0e38f; int nj = 0x7fffffff;
      #pragma unroll
      for (int n = 0; n < 4; ++n) {
        const float d2 = fmaxf(sqiv + sqjv[n] - 2.0f * acc[m][n][r], 0.0f);
        const int j = jglob[n];
        const bool isPos = diag && ((j >> 4) == (gi >> 4));
        if (isPos) {
          if (d2 > pv || (d2 == pv && j < pj)) { pv = d2; pj = j; }
        } else {
          if (d2 < nv || (d2 == nv && j < nj)) { nv = d2; nj = j; }
        }
      }
      // butterfly over the 16-lane column group (rows identical within group)
      #pragma unroll
      for (int off = 1; off < 16; off <<= 1) {
        float ov = __shfl_xor(nv, off); int oj = __shfl_xor(nj, off);
        if (ov < nv || (ov == nv && oj < nj)) { nv = ov; nj = oj; }
        float pov = __shfl_xor(pv, off); int poj = __shfl_xor(pj, off);
        if (pov > pv || (pov == pv && ((unsigned)poj < (unsigned)pj))) { pv = pov; pj = poj; }
      }
      if ((lane & 15) == 0) {
        atomicMin(&negk[gi], ((u64)__float_as_uint(nv) << 32) | (unsigned)nj);
        if (diag && pj >= 0)
          atomicMax(&posk[gi], ((u64)__float_as_uint(pv) << 32) | (unsigned)(0xFFFFFFFFu - (unsigned)pj));
      }
    }
  }
}

// ---------------- kernel 2: exact fp32 triplet terms, wave per row ----------
__global__ __launch_bounds__(256) void triplet_kernel(const float* __restrict__ emb,
                                                      const u64* __restrict__ posk,
                                                      const u64* __restrict__ negk,
                                                      float* __restrict__ hinge) {
  int i = (blockIdx.x * 256 + threadIdx.x) >> 6;
  int lane = threadIdx.x & 63;
  if (i >= NN) return;

  u64 pk = posk[i], nk = negk[i];
  int p = (int)(0xFFFFFFFFu - (unsigned)(pk & 0xFFFFFFFFu));
  int nidx = (int)(nk & 0xFFFFFFFFu);

  float4 e  = *reinterpret_cast<const float4*>(emb + (size_t)i * DD + 4 * lane);
  float4 ep = *reinterpret_cast<const float4*>(emb + (size_t)p * DD + 4 * lane);
  float4 en = *reinterpret_cast<const float4*>(emb + (size_t)nidx * DD + 4 * lane);

  float dpx = e.x - ep.x + EPSV, dpy = e.y - ep.y + EPSV,
        dpz = e.z - ep.z + EPSV, dpw = e.w - ep.w + EPSV;
  float dnx = e.x - en.x + EPSV, dny = e.y - en.y + EPSV,
        dnz = e.z - en.z + EPSV, dnw = e.w - en.w + EPSV;
  float sp = dpx * dpx + dpy * dpy + dpz * dpz + dpw * dpw;
  float sn = dnx * dnx + dny * dny + dnz * dnz + dnw * dnw;
  #pragma unroll
  for (int off = 32; off; off >>= 1) {
    sp += __shfl_xor(sp, off);
    sn += __shfl_xor(sn, off);
  }
  if (lane == 0) {
    float d_ap = sqrtf(sp), d_an = sqrtf(sn);
    hinge[i] = fmaxf(d_ap - d_an + 1.0f, 0.0f);
  }
}

// ---------------- kernel 3: deterministic mean ----------------
__global__ __launch_bounds__(256) void reduce_kernel(const float* __restrict__ hinge,
                                                     float* __restrict__ out) {
  __shared__ float sdata[256];
  float s = 0.0f;
  for (int k = threadIdx.x; k < NN; k += 256) s += hinge[k];
  sdata[threadIdx.x] = s;
  __syncthreads();
  for (int st = 128; st; st >>= 1) {
    if (threadIdx.x < st) sdata[threadIdx.x] += sdata[threadIdx.x + st];
    __syncthreads();
  }
  if (threadIdx.x == 0) out[0] = sdata[0] * (1.0f / NN);
}

extern "C" void kernel_launch(void* const* d_in, const int* in_sizes, int n_in,
                              void* d_out, int out_size, void* d_ws, size_t ws_size,
                              hipStream_t stream) {
  const float* emb = (const float*)d_in[0];  // [N, D] row-major
  char* ws = (char*)d_ws;
  float* sq   = (float*)ws;                  // 16 KB
  u64* posk   = (u64*)(ws + 16384);          // 32 KB
  u64* negk   = (u64*)(ws + 16384 + 32768);  // 32 KB
  float* hinge = (float*)(ws + 16384 + 65536); // 16 KB
  float* out = (float*)d_out;

  sqnorm_kernel<<<NN / 4, 256, 0, stream>>>(emb, sq, posk, negk);
  mine_mfma_kernel<<<32 * 32, 256, 0, stream>>>(emb, sq, posk, negk);
  triplet_kernel<<<NN / 4, 256, 0, stream>>>(emb, posk, negk, hinge);
  reduce_kernel<<<1, 256, 0, stream>>>(hinge, out);
}

// Round 3
// 110.437 us; speedup vs baseline: 2.1990x; 1.0632x over previous
//
#include <hip/hip_runtime.h>
#include <math.h>

#define CC 256
#define KK 16
#define DD 256
#define NN 4096
#define EPSV 1e-6f

typedef unsigned long long u64;
typedef __attribute__((ext_vector_type(8))) short short8v;
typedef __attribute__((ext_vector_type(8))) unsigned short ushort8v;
typedef __attribute__((ext_vector_type(4))) float f32x4;

// ---------------- kernel 0: squared norms + init mining keys ----------------
__global__ __launch_bounds__(256) void sqnorm_kernel(const float* __restrict__ emb,
                                                     float* __restrict__ sq,
                                                     u64* __restrict__ posk,
                                                     u64* __restrict__ negk) {
  int gw = (blockIdx.x * 256 + threadIdx.x) >> 6;  // row
  int lane = threadIdx.x & 63;
  if (gw >= NN) return;
  float4 v = *reinterpret_cast<const float4*>(emb + (size_t)gw * DD + 4 * lane);
  float s = v.x * v.x + v.y * v.y + v.z * v.z + v.w * v.w;
  #pragma unroll
  for (int off = 32; off; off >>= 1) s += __shfl_xor(s, off);
  if (lane == 0) sq[gw] = s;
  if (lane == 1) posk[gw] = 0ull;   // max-key init
  if (lane == 2) negk[gw] = ~0ull;  // min-key init
}

// ---------------- kernel 1: split fp32 -> (hi,lo) bf16 in MFMA fragment order
// Fragment layout for mfma_f32_16x16x32_bf16 (A and B coincide for Gram):
//   lane l of fragment (rowgroup g, kslice s) holds
//   E[16g + (l&15)][32s + (l>>4)*8 .. +7]
// Stored flat: frag[((g*8 + s)*64 + l)*8 + e]
__global__ __launch_bounds__(256) void prep_kernel(const float* __restrict__ emb,
                                                   unsigned short* __restrict__ hi,
                                                   unsigned short* __restrict__ lo) {
  int c = blockIdx.x * 256 + threadIdx.x;  // 0..131071 lane-chunks
  int l = c & 63;
  int s = (c >> 6) & 7;
  int g = c >> 9;
  int row = 16 * g + (l & 15);
  int k0 = 32 * s + (l >> 4) * 8;
  const float* src = emb + (size_t)row * DD + k0;
  float4 v0 = *reinterpret_cast<const float4*>(src);
  float4 v1 = *reinterpret_cast<const float4*>(src + 4);
  float f[8] = {v0.x, v0.y, v0.z, v0.w, v1.x, v1.y, v1.z, v1.w};
  ushort8v h, ll;
  #pragma unroll
  for (int i = 0; i < 8; ++i) {
    unsigned b = __float_as_uint(f[i]);
    h[i] = (unsigned short)(b >> 16);                     // truncate to bf16
    float fl = f[i] - __uint_as_float(b & 0xFFFF0000u);   // exact residual
    ll[i] = (unsigned short)(__float_as_uint(fl) >> 16);
  }
  *reinterpret_cast<ushort8v*>(hi + (size_t)c * 8) = h;
  *reinterpret_cast<ushort8v*>(lo + (size_t)c * 8) = ll;
}

// ---------------- kernel 2: MFMA gram-tile mining, triangular grid ----------
// 528 blocks = upper triangle of 32x32 tiles of 128x128. 4 waves = 2x2 of 64x64.
// Operands loaded straight from fragment-ordered global arrays (no LDS).
__device__ __forceinline__ const short8v* fragp(const unsigned short* base, int g,
                                                int s, int lane) {
  return reinterpret_cast<const short8v*>(base + (((size_t)(g * 8 + s) * 64 + lane) * 8));
}

__global__ __launch_bounds__(256, 2) void mine_mfma_kernel(const unsigned short* __restrict__ hi,
                                                           const unsigned short* __restrict__ lo,
                                                           const float* __restrict__ sq,
                                                           u64* __restrict__ posk,
                                                           u64* __restrict__ negk) {
  // unrank upper-triangular tile index
  int rem = blockIdx.x;
  int ib = 0;
  #pragma unroll 1
  for (int r = 0; r < 32; ++r) {
    int cnt = 32 - r;
    if (rem < cnt) { ib = r; break; }
    rem -= cnt;
  }
  const int jb = ib + rem;
  const bool diag = (ib == jb);
  const int ibRow = ib * 128, jbRow = jb * 128;

  const int tid = threadIdx.x;
  const int lane = tid & 63;
  const int w = tid >> 6;
  const int wm = w >> 1, wn = w & 1;
  const int fr = lane & 15;
  const int grp = lane >> 4;

  int gA[4], gB[4];
  #pragma unroll
  for (int m = 0; m < 4; ++m) gA[m] = ib * 8 + wm * 4 + m;
  #pragma unroll
  for (int n = 0; n < 4; ++n) gB[n] = jb * 8 + wn * 4 + n;

  f32x4 acc[4][4];
  #pragma unroll
  for (int m = 0; m < 4; ++m)
    #pragma unroll
    for (int n = 0; n < 4; ++n)
      acc[m][n] = (f32x4){0.f, 0.f, 0.f, 0.f};

  #pragma unroll 2
  for (int s = 0; s < 8; ++s) {
    short8v ahi[4], alo[4], bhi[4], blo[4];
    #pragma unroll
    for (int m = 0; m < 4; ++m) {
      ahi[m] = *fragp(hi, gA[m], s, lane);
      alo[m] = *fragp(lo, gA[m], s, lane);
    }
    #pragma unroll
    for (int n = 0; n < 4; ++n) {
      bhi[n] = *fragp(hi, gB[n], s, lane);
      blo[n] = *fragp(lo, gB[n], s, lane);
    }
    #pragma unroll
    for (int m = 0; m < 4; ++m)
      #pragma unroll
      for (int n = 0; n < 4; ++n) {
        acc[m][n] = __builtin_amdgcn_mfma_f32_16x16x32_bf16(ahi[m], bhi[n], acc[m][n], 0, 0, 0);
        acc[m][n] = __builtin_amdgcn_mfma_f32_16x16x32_bf16(ahi[m], blo[n], acc[m][n], 0, 0, 0);
        acc[m][n] = __builtin_amdgcn_mfma_f32_16x16x32_bf16(alo[m], bhi[n], acc[m][n], 0, 0, 0);
      }
  }

  // ---- epilogue on d^2 (sqrt is monotone; ties preserved) ----
  // C layout: col = lane&15, row = (lane>>4)*4 + reg
  float sqjv[4]; int jglob[4];
  #pragma unroll
  for (int n = 0; n < 4; ++n) {
    jglob[n] = jbRow + wn * 64 + n * 16 + fr;
    sqjv[n] = sq[jglob[n]];
  }
  float sqiv[4][4]; int iglob[4][4];
  #pragma unroll
  for (int m = 0; m < 4; ++m)
    #pragma unroll
    for (int r = 0; r < 4; ++r) {
      iglob[m][r] = ibRow + wm * 64 + m * 16 + grp * 4 + r;
      sqiv[m][r] = sq[iglob[m][r]];
    }

  // row scan: rows of ib-group vs cols of jb-group
  #pragma unroll
  for (int m = 0; m < 4; ++m) {
    #pragma unroll
    for (int r = 0; r < 4; ++r) {
      const int gi = iglob[m][r];
      float pv = -1.0f; int pj = -1;
      float nv = 3.0e38f; int nj = 0x7fffffff;
      #pragma unroll
      for (int n = 0; n < 4; ++n) {
        const float d2 = fmaxf(sqiv[m][r] + sqjv[n] - 2.0f * acc[m][n][r], 0.0f);
        const int j = jglob[n];
        const bool isPos = diag && ((j >> 4) == (gi >> 4));
        if (isPos) {
          if (d2 > pv || (d2 == pv && j < pj)) { pv = d2; pj = j; }
        } else {
          if (d2 < nv || (d2 == nv && j < nj)) { nv = d2; nj = j; }
        }
      }
      #pragma unroll
      for (int off = 1; off < 16; off <<= 1) {
        float ov = __shfl_xor(nv, off); int oj = __shfl_xor(nj, off);
        if (ov < nv || (ov == nv && oj < nj)) { nv = ov; nj = oj; }
        float pov = __shfl_xor(pv, off); int poj = __shfl_xor(pj, off);
        if (pov > pv || (pov == pv && ((unsigned)poj < (unsigned)pj))) { pv = pov; pj = poj; }
      }
      if (fr == 0) {
        if (nj != 0x7fffffff)
          atomicMin(&negk[gi], ((u64)__float_as_uint(nv) << 32) | (unsigned)nj);
        if (diag && pj >= 0)
          atomicMax(&posk[gi], ((u64)__float_as_uint(pv) << 32) |
                                   (unsigned)(0xFFFFFFFFu - (unsigned)pj));
      }
    }
  }

  // column scan (transpose side), off-diagonal tiles only: all negatives
  if (!diag) {
    #pragma unroll
    for (int n = 0; n < 4; ++n) {
      float nv = 3.0e38f; int ni = 0x7fffffff;
      #pragma unroll
      for (int m = 0; m < 4; ++m)
        #pragma unroll
        for (int r = 0; r < 4; ++r) {
          const float d2 = fmaxf(sqiv[m][r] + sqjv[n] - 2.0f * acc[m][n][r], 0.0f);
          if (d2 < nv || (d2 == nv && iglob[m][r] < ni)) { nv = d2; ni = iglob[m][r]; }
        }
      #pragma unroll
      for (int off = 16; off < 64; off <<= 1) {
        float ov = __shfl_xor(nv, off); int oi = __shfl_xor(ni, off);
        if (ov < nv || (ov == nv && oi < ni)) { nv = ov; ni = oi; }
      }
      if (grp == 0)
        atomicMin(&negk[jglob[n]], ((u64)__float_as_uint(nv) << 32) | (unsigned)ni);
    }
  }
}

// ---------------- kernel 3: exact fp32 triplet terms, wave per row ----------
__global__ __launch_bounds__(256) void triplet_kernel(const float* __restrict__ emb,
                                                      const u64* __restrict__ posk,
                                                      const u64* __restrict__ negk,
                                                      float* __restrict__ hinge) {
  int i = (blockIdx.x * 256 + threadIdx.x) >> 6;
  int lane = threadIdx.x & 63;
  if (i >= NN) return;

  u64 pk = posk[i], nk = negk[i];
  int p = (int)(0xFFFFFFFFu - (unsigned)(pk & 0xFFFFFFFFu));
  int nidx = (int)(nk & 0xFFFFFFFFu);

  float4 e  = *reinterpret_cast<const float4*>(emb + (size_t)i * DD + 4 * lane);
  float4 ep = *reinterpret_cast<const float4*>(emb + (size_t)p * DD + 4 * lane);
  float4 en = *reinterpret_cast<const float4*>(emb + (size_t)nidx * DD + 4 * lane);

  float dpx = e.x - ep.x + EPSV, dpy = e.y - ep.y + EPSV,
        dpz = e.z - ep.z + EPSV, dpw = e.w - ep.w + EPSV;
  float dnx = e.x - en.x + EPSV, dny = e.y - en.y + EPSV,
        dnz = e.z - en.z + EPSV, dnw = e.w - en.w + EPSV;
  float sp = dpx * dpx + dpy * dpy + dpz * dpz + dpw * dpw;
  float sn = dnx * dnx + dny * dny + dnz * dnz + dnw * dnw;
  #pragma unroll
  for (int off = 32; off; off >>= 1) {
    sp += __shfl_xor(sp, off);
    sn += __shfl_xor(sn, off);
  }
  if (lane == 0) {
    float d_ap = sqrtf(sp), d_an = sqrtf(sn);
    hinge[i] = fmaxf(d_ap - d_an + 1.0f, 0.0f);
  }
}

// ---------------- kernel 4: deterministic mean ----------------
__global__ __launch_bounds__(256) void reduce_kernel(const float* __restrict__ hinge,
                                                     float* __restrict__ out) {
  __shared__ float sdata[256];
  float s = 0.0f;
  for (int k = threadIdx.x; k < NN; k += 256) s += hinge[k];
  sdata[threadIdx.x] = s;
  __syncthreads();
  for (int st = 128; st; st >>= 1) {
    if (threadIdx.x < st) sdata[threadIdx.x] += sdata[threadIdx.x + st];
    __syncthreads();
  }
  if (threadIdx.x == 0) out[0] = sdata[0] * (1.0f / NN);
}

extern "C" void kernel_launch(void* const* d_in, const int* in_sizes, int n_in,
                              void* d_out, int out_size, void* d_ws, size_t ws_size,
                              hipStream_t stream) {
  const float* emb = (const float*)d_in[0];  // [N, D] row-major
  char* ws = (char*)d_ws;
  float* sq    = (float*)ws;                    // 16 KB
  u64* posk    = (u64*)(ws + (16 << 10));       // 32 KB
  u64* negk    = (u64*)(ws + (48 << 10));       // 32 KB
  float* hinge = (float*)(ws + (80 << 10));     // 16 KB
  unsigned short* hi = (unsigned short*)(ws + (96 << 10));             // 2 MB
  unsigned short* lo = (unsigned short*)(ws + (96 << 10) + (2 << 20)); // 2 MB
  float* out = (float*)d_out;

  sqnorm_kernel<<<NN / 4, 256, 0, stream>>>(emb, sq, posk, negk);
  prep_kernel<<<512, 256, 0, stream>>>(emb, hi, lo);
  mine_mfma_kernel<<<528, 256, 0, stream>>>(hi, lo, sq, posk, negk);
  triplet_kernel<<<NN / 4, 256, 0, stream>>>(emb, posk, negk, hinge);
  reduce_kernel<<<1, 256, 0, stream>>>(hinge, out);
}